// Round 3
// baseline (235.477 us; speedup 1.0000x reference)
//
#include <hip/hip_runtime.h>
#include <math.h>

#define NB 8192
#define BATCH 2
#define KNN 20
#define BN (BATCH*NB)
#define NE (BN*KNN)        // 327680 edges
#define GT 16              // tiles per staged group (16 KB)
#define NG 8               // groups per pass
#define BIG 3.0e38f

__device__ __forceinline__ float gelu_f(float x){
    float x3 = x*x*x;
    float a = 0.7978845608028654f*(x + 0.044715f*x3);
    float e2 = __expf(2.0f*a);
    float th = 1.0f - __fdividef(2.0f, e2+1.0f);
    return 0.5f*x*(1.0f+th);
}

// ---------------- K1: prep (all 64 blocks) + cond MLP (blocks 0,1) ----------------
// consts floats: C[2][128]@0, S1[128]@256, S2[128]@384, D[2][64]@512, T1[64]@640
// pack per h (128): {C0,C1,S1,S2, W72,W73,W74,W75, V0,V1,V2,V3} = 12 floats
__global__ __launch_bounds__(256) void prepcond_kernel(const float* __restrict__ z,
        const float* __restrict__ t,
        const float* __restrict__ conditioning,
        const float* __restrict__ Wc1, const float* __restrict__ bc1,
        const float* __restrict__ Wc2, const float* __restrict__ bc2,
        const float* __restrict__ Wc3, const float* __restrict__ bc3,
        const float* __restrict__ We1, const float* __restrict__ be1,
        const float* __restrict__ We2,
        const float* __restrict__ Wn1, const float* __restrict__ bn1,
        float4* __restrict__ pos4, float4* __restrict__ vel4,
        float* __restrict__ consts, float* __restrict__ pack){
    int tid = threadIdx.x;
    int g = blockIdx.x*256 + tid;
    const float* zp = z + (size_t)g*7;
    float x = zp[0], y = zp[1], zz = zp[2];
    float r2 = x*x + y*y + zz*zz;
    pos4[g] = make_float4(x, y, zz, r2);
    vel4[g] = make_float4(zp[3], zp[4], zp[5], zp[6]);

    if (blockIdx.x >= BATCH) return;
    int b = blockIdx.x;
    __shared__ float ci[36];
    __shared__ float h1[144];
    __shared__ float h2[144];
    __shared__ float cnd[36];
    float tv = t[b];
    if (tid < 16){
        float f = expf(-9.210340371976184f * (float)tid / 15.0f);
        float a = tv*f;
        ci[tid]    = sinf(a);
        ci[16+tid] = cosf(a);
    }
    if (tid < 4) ci[32+tid] = conditioning[b*4+tid];
    __syncthreads();
    if (tid < 144){
        float acc = bc1[tid];
        #pragma unroll
        for (int c=0;c<36;c++) acc += ci[c]*Wc1[c*144+tid];
        h1[tid] = gelu_f(acc);
    }
    __syncthreads();
    if (tid < 144){
        float acc = bc2[tid];
        #pragma unroll 36
        for (int c=0;c<144;c++) acc += h1[c]*Wc2[c*144+tid];
        h2[tid] = gelu_f(acc);
    }
    __syncthreads();
    if (tid < 36){
        float acc = bc3[tid];
        #pragma unroll 36
        for (int c=0;c<144;c++) acc += h2[c]*Wc3[c*36+tid];
        cnd[tid] = acc;
    }
    __syncthreads();
    if (tid < 128){
        float accC = be1[tid], s1 = 0.f, s2 = 0.f;
        #pragma unroll
        for (int c=0;c<36;c++){
            float w1 = We1[c*128+tid];
            float w2 = We1[(36+c)*128+tid];
            accC += cnd[c]*(w1+w2);
            s1 += w1; s2 += w2;
        }
        consts[b*128+tid] = accC;
        pack[tid*12 + b] = accC;
        if (b==0){
            consts[256+tid] = s1; consts[384+tid] = s2;
            pack[tid*12+2] = s1;
            pack[tid*12+3] = s2;
            pack[tid*12+4] = We1[72*128+tid];
            pack[tid*12+5] = We1[73*128+tid];
            pack[tid*12+6] = We1[74*128+tid];
            pack[tid*12+7] = We1[75*128+tid];
            pack[tid*12+8]  = We2[tid*4+0];
            pack[tid*12+9]  = We2[tid*4+1];
            pack[tid*12+10] = We2[tid*4+2];
            pack[tid*12+11] = We2[tid*4+3];
        }
    }
    if (tid < 64){
        float accD = bn1[tid], t1 = 0.f;
        #pragma unroll
        for (int c=0;c<36;c++){
            float w = Wn1[c*64+tid];
            accD += cnd[c]*w;
            t1 += w;
        }
        consts[512 + b*64 + tid] = accD;
        if (b==0) consts[640+tid] = t1;
    }
}

// ---------------- K2: fused KNN + select (two-pass), 8 waves x 8 nodes ----------------
// Distance: per-target-shifted d2' = r_j^2 - 2 p_i.p_j (ordering-equivalent per target;
// threshold from same shifted values -> identical selection). 3 FMA + min per candidate.
// 8 nodes/wave: each ds_read_b128 amortizes over 8 distances (was 4).
// Block = 512 thr / 8 waves = 64 nodes (exactly one tile -> one selfTile), grid = BN/64.
// NOTE: prefetch stays in named scalars (pre0/pre1) — array form goes to scratch (rule #20).
__global__ __launch_bounds__(512, 4) void knn_kernel(const float4* __restrict__ pos4,
                                                     int* __restrict__ nbr){
    __shared__ float4 sPos[GT*64];      // 16 KB
    __shared__ float2 sCand[64*64];     // 32 KB
    int tid = threadIdx.x;
    int w = tid >> 6, lane = tid & 63;
    int n0g = blockIdx.x * 64;
    int b = n0g >> 13;
    int n0 = n0g & (NB-1);
    const float4* __restrict__ P = pos4 + b*NB;

    int nw = n0 + w*8;
    float nx[8], ny[8], nz[8], acc[8];
    #pragma unroll
    for (int k=0;k<8;k++){
        float4 p = P[nw+k];
        nx[k] = -2.0f*p.x; ny[k] = -2.0f*p.y; nz[k] = -2.0f*p.z;
        acc[k] = BIG;
    }
    int selfTile = n0 >> 6;            // all 64 block nodes share one tile
    int sl0 = w*8;                     // self lane for node k is sl0+k (n0 % 64 == 0)

    // ---- Pass A ----
    float4 pre0 = P[(w*2    )*64 + lane];
    float4 pre1 = P[(w*2 + 1)*64 + lane];
    for (int g=0; g<NG; ++g){
        __syncthreads();
        sPos[(w*2    )*64 + lane] = pre0;
        sPos[(w*2 + 1)*64 + lane] = pre1;
        if (g+1 < NG){
            pre0 = P[((g+1)*GT + w*2    )*64 + lane];
            pre1 = P[((g+1)*GT + w*2 + 1)*64 + lane];
        }
        __syncthreads();
        int tbase = g*GT;
        #pragma unroll
        for (int t=0;t<GT;t++){
            float4 q = sPos[t*64 + lane];
            if (tbase + t != selfTile){
                #pragma unroll
                for (int k=0;k<8;k++){
                    float d2 = fmaf(nx[k],q.x, fmaf(ny[k],q.y, fmaf(nz[k],q.z, q.w)));
                    acc[k] = fminf(acc[k], d2);
                }
            } else {
                #pragma unroll
                for (int k=0;k<8;k++){
                    float d2 = fmaf(nx[k],q.x, fmaf(ny[k],q.y, fmaf(nz[k],q.z, q.w)));
                    if (lane == sl0 + k) d2 = BIG;
                    acc[k] = fminf(acc[k], d2);
                }
            }
        }
    }

    // ---- T[k] = 20th smallest of 64 per-lane minima ----
    float T[8];
    #pragma unroll
    for (int k=0;k<8;k++){
        float v = acc[k];
        #pragma unroll
        for (int K=2; K<=64; K<<=1){
            #pragma unroll
            for (int j=K>>1; j>0; j>>=1){
                float o = __shfl_xor(v, j);
                bool keepmin = (((lane & j) == 0) == ((lane & K) == 0));
                float mn = fminf(v,o), mx = fmaxf(v,o);
                v = keepmin ? mn : mx;
            }
        }
        T[k] = __shfl(v, 19);
    }

    // ---- Pass B: collect into LDS ----
    int cnt[8];
    #pragma unroll
    for (int k=0;k<8;k++) cnt[k] = 0;
    unsigned long long lt = (1ull << lane) - 1ull;

    pre0 = P[(w*2    )*64 + lane];
    pre1 = P[(w*2 + 1)*64 + lane];
    for (int g=0; g<NG; ++g){
        __syncthreads();
        sPos[(w*2    )*64 + lane] = pre0;
        sPos[(w*2 + 1)*64 + lane] = pre1;
        if (g+1 < NG){
            pre0 = P[((g+1)*GT + w*2    )*64 + lane];
            pre1 = P[((g+1)*GT + w*2 + 1)*64 + lane];
        }
        __syncthreads();
        int tbase = g*GT;
        #pragma unroll 4
        for (int t=0;t<GT;t++){
            int tile = tbase + t;
            float4 q = sPos[t*64 + lane];
            int j = (tile<<6) + lane;
            bool selft = (tile == selfTile);
            #pragma unroll
            for (int k=0;k<8;k++){
                float d2 = fmaf(nx[k],q.x, fmaf(ny[k],q.y, fmaf(nz[k],q.z, q.w)));
                bool hit = (d2 <= T[k]);
                if (selft && (lane == sl0 + k)) hit = false;
                unsigned long long m = __ballot(hit);
                if (m){
                    if (hit){
                        int off = cnt[k] + (int)__popcll(m & lt);
                        if (off < 64)
                            sCand[(w*8+k)*64 + off] = make_float2(d2, __int_as_float(j));
                    }
                    cnt[k] += (int)__popcll(m);
                }
            }
        }
    }

    // ---- sort each node's candidates (same-wave data; no barrier needed) ----
    #pragma unroll
    for (int k=0;k<8;k++){
        int m = cnt[k]; if (m > 64) m = 64;
        float d; int idx;
        if (lane < m){
            float2 e = sCand[(w*8+k)*64 + lane];
            d = e.x; idx = __float_as_int(e.y);
        } else { d = BIG; idx = 0x7f000000 + lane; }
        #pragma unroll
        for (int K=2; K<=64; K<<=1){
            #pragma unroll
            for (int j=K>>1; j>0; j>>=1){
                float od = __shfl_xor(d, j);
                int   oi = __shfl_xor(idx, j);
                bool pless = (od < d) || (od == d && oi < idx);
                bool keepmin = (((lane & j) == 0) == ((lane & K) == 0));
                if (pless == keepmin){ d = od; idx = oi; }
            }
        }
        if (lane < KNN) nbr[(size_t)(n0g + w*8 + k)*KNN + lane] = idx;
    }
}

// ---------------- K3: fused edge MLP + softmax-aggregate + node MLP + output ----------------
// 1024 blocks x 320 threads; block owns 16 nodes = 320 edges exactly.
// Edge-MLP weights are wave-uniform per h -> read directly from global (pack) with
// uniform addresses so they go through the scalar s_load/constant-cache path,
// keeping the LDS pipe free (was 3x ds_read_b128 per h = the kernel's bottleneck).
__global__ __launch_bounds__(320) void edgenode_kernel(const float4* __restrict__ pos4,
        const float4* __restrict__ vel4,
        const int* __restrict__ nbr,
        const float* __restrict__ pack,
        const float* __restrict__ consts,
        const float* __restrict__ Wn1,
        const float* __restrict__ Wn2,
        const float* __restrict__ be2,
        const float* __restrict__ bn2,
        const float* __restrict__ alpha_p,
        const float* __restrict__ beta_p,
        const float* __restrict__ z,
        float* __restrict__ out){
    __shared__ float sLg[320], sSm[320], sUx[320], sUy[320], sUz[320];  // 6.25 KB
    __shared__ float sD[64], sT1[64], sW36[64], sWo[64];
    __shared__ float sMf[16];
    __shared__ float4 sAgg[16];                      // {vax,vay,vaz,sagg}
    __shared__ float sPart[320];

    int tid = threadIdx.x;
    bool bb = (blockIdx.x >= 512);                   // batch block-uniform
    const float4* __restrict__ pk = (const float4*)pack;
    if (tid < 64){
        sD[tid]   = consts[512 + (bb?64:0) + tid];
        sT1[tid]  = consts[640+tid];
        sW36[tid] = Wn1[36*64+tid];
        sWo[tid]  = Wn2[tid];
    }

    int e = blockIdx.x*320 + tid;
    int i = e / KNN;                   // global tgt node
    int ln = tid / KNN;                // local node 0..15
    int r  = tid - ln*KNN;             // edge rank 0..19
    int bbase = bb ? NB : 0;
    int s = nbr[e];
    float4 ps = pos4[bbase + s], pt = pos4[i];
    float4 vs = vel4[bbase + s], vt = vel4[i];
    if (r == 0) sMf[ln] = vt.w;

    float rx = ps.x - pt.x, ry = ps.y - pt.y, rz = ps.z - pt.z;
    float r2  = rx*rx + ry*ry + rz*rz;
    float vv  = vs.x*vt.x + vs.y*vt.y + vs.z*vt.z;
    float vsr = vs.x*rx + vs.y*ry + vs.z*rz;
    float vtr = vt.x*rx + vt.y*ry + vt.z*rz;
    float mfs = vs.w, mft = vt.w;

    float a0 = be2[0], a1 = be2[1], a2 = be2[2], a3 = be2[3];
    #pragma unroll 4
    for (int h=0; h<128; h++){
        float4 A  = pk[h*3];
        float4 Bv = pk[h*3+1];
        float4 C  = pk[h*3+2];
        float base = bb ? A.y : A.x;
        float x = base + mfs*A.z + mft*A.w + r2*Bv.x + vv*Bv.y + vsr*Bv.z + vtr*Bv.w;
        float gx = gelu_f(x);
        a0 += gx*C.x; a1 += gx*C.y; a2 += gx*C.z; a3 += gx*C.w;
    }
    sLg[tid] = a0;
    sSm[tid] = a1;
    sUx[tid] = a2*rx + a3*vs.x;
    sUy[tid] = a2*ry + a3*vs.y;
    sUz[tid] = a2*rz + a3*vs.z;
    __syncthreads();

    // per-node softmax + aggregation (16 serial lanes)
    if (tid < 16){
        int base = tid*KNN;
        float m = -BIG;
        #pragma unroll
        for (int q=0;q<KNN;q++) m = fmaxf(m, sLg[base+q]);
        float den=0.f, wx=0.f, wy=0.f, wz=0.f, wsm=0.f;
        #pragma unroll
        for (int q=0;q<KNN;q++){
            float a = __expf(sLg[base+q]-m);
            den += a;
            wsm += a*sSm[base+q];
            wx  += a*sUx[base+q];
            wy  += a*sUy[base+q];
            wz  += a*sUz[base+q];
        }
        float inv = __fdividef(1.0f, den);
        sAgg[tid] = make_float4(wx*inv, wy*inv, wz*inv, wsm*inv);
    }
    __syncthreads();

    // node MLP partials: 20 threads per node, h = r, r+20, r+40, (r+60)
    {
        float mf = sMf[ln];
        float sg = sAgg[ln].w;
        float part = 0.f;
        #pragma unroll
        for (int h=r; h<64; h+=KNN){
            float x = sD[h] + mf*sT1[h] + sg*sW36[h];
            part += gelu_f(x)*sWo[h];
        }
        sPart[tid] = part;
    }
    __syncthreads();

    if (tid < 16){
        float sout = bn2[0];
        #pragma unroll
        for (int q=0;q<KNN;q++) sout += sPart[tid*KNN+q];
        int node = blockIdx.x*16 + tid;
        float alpha = alpha_p[0], beta = beta_p[0];
        float4 ag = sAgg[tid];
        const float* zp = z + (size_t)node*7;
        float* op = out + (size_t)node*7;
        op[0] = zp[0]*2.0f + alpha*ag.x;
        op[1] = zp[1]*2.0f + alpha*ag.y;
        op[2] = zp[2]*2.0f + alpha*ag.z;
        op[3] = zp[3] + beta*ag.x;
        op[4] = zp[4] + beta*ag.y;
        op[5] = zp[5] + beta*ag.z;
        op[6] = zp[6] + sout;
    }
}

extern "C" void kernel_launch(void* const* d_in, const int* in_sizes, int n_in,
                              void* d_out, int out_size, void* d_ws, size_t ws_size,
                              hipStream_t stream) {
    const float* z    = (const float*)d_in[0];
    const float* t    = (const float*)d_in[1];
    const float* cond = (const float*)d_in[2];
    const float* Wc1  = (const float*)d_in[4];
    const float* bc1  = (const float*)d_in[5];
    const float* Wc2  = (const float*)d_in[6];
    const float* bc2  = (const float*)d_in[7];
    const float* Wc3  = (const float*)d_in[8];
    const float* bc3  = (const float*)d_in[9];
    const float* We1  = (const float*)d_in[10];
    const float* be1  = (const float*)d_in[11];
    const float* We2  = (const float*)d_in[12];
    const float* be2  = (const float*)d_in[13];
    const float* Wn1  = (const float*)d_in[14];
    const float* bn1  = (const float*)d_in[15];
    const float* Wn2  = (const float*)d_in[16];
    const float* bn2  = (const float*)d_in[17];
    const float* alp  = (const float*)d_in[18];
    const float* bet  = (const float*)d_in[19];
    float* out = (float*)d_out;

    char* ws = (char*)d_ws;
    float4* pos4   = (float4*)(ws);                      // 262144 B
    float4* vel4   = (float4*)(ws + 262144);             // 262144 B
    float*  consts = (float*)(ws + 524288);              // 4096 B
    float*  pack   = (float*)(ws + 528384);              // 6144 B
    int*    nbr    = (int*)(ws + 534528);                // 1310720 B

    prepcond_kernel<<<dim3(BN/256), dim3(256), 0, stream>>>(z, t, cond,
        Wc1, bc1, Wc2, bc2, Wc3, bc3, We1, be1, We2, Wn1, bn1,
        pos4, vel4, consts, pack);
    knn_kernel<<<dim3(BN/64), dim3(512), 0, stream>>>(pos4, nbr);
    edgenode_kernel<<<dim3(BN/16), dim3(320), 0, stream>>>(pos4, vel4, nbr, pack, consts,
        Wn1, Wn2, be2, bn2, alp, bet, z, out);
}

// Round 4
// 207.520 us; speedup vs baseline: 1.1347x; 1.1347x over previous
//
#include <hip/hip_runtime.h>
#include <math.h>

#define NB 8192
#define BATCH 2
#define KNN 20
#define BN (BATCH*NB)
#define NE (BN*KNN)        // 327680 edges
#define GT 16              // tiles per staged group (16 KB)
#define NG 8               // groups per pass
#define BIG 3.0e38f

__device__ __forceinline__ float gelu_f(float x){
    float x3 = x*x*x;
    float a = 0.7978845608028654f*(x + 0.044715f*x3);
    float e2 = __expf(2.0f*a);
    float th = 1.0f - __fdividef(2.0f, e2+1.0f);
    return 0.5f*x*(1.0f+th);
}

// ---------------- K1: prep (all 64 blocks) + cond MLP (blocks 0,1) ----------------
// consts floats: C[2][128]@0, S1[128]@256, S2[128]@384, D[2][64]@512, T1[64]@640
// pack per h (128): {C0,C1,S1,S2, W72,W73,W74,W75, V0,V1,V2,V3} = 12 floats
__global__ __launch_bounds__(256) void prepcond_kernel(const float* __restrict__ z,
        const float* __restrict__ t,
        const float* __restrict__ conditioning,
        const float* __restrict__ Wc1, const float* __restrict__ bc1,
        const float* __restrict__ Wc2, const float* __restrict__ bc2,
        const float* __restrict__ Wc3, const float* __restrict__ bc3,
        const float* __restrict__ We1, const float* __restrict__ be1,
        const float* __restrict__ We2,
        const float* __restrict__ Wn1, const float* __restrict__ bn1,
        float4* __restrict__ pos4, float4* __restrict__ vel4,
        float* __restrict__ consts, float* __restrict__ pack){
    int tid = threadIdx.x;
    int g = blockIdx.x*256 + tid;
    const float* zp = z + (size_t)g*7;
    float x = zp[0], y = zp[1], zz = zp[2];
    float r2 = x*x + y*y + zz*zz;
    pos4[g] = make_float4(x, y, zz, r2);
    vel4[g] = make_float4(zp[3], zp[4], zp[5], zp[6]);

    if (blockIdx.x >= BATCH) return;
    int b = blockIdx.x;
    __shared__ float ci[36];
    __shared__ float h1[144];
    __shared__ float h2[144];
    __shared__ float cnd[36];
    float tv = t[b];
    if (tid < 16){
        float f = expf(-9.210340371976184f * (float)tid / 15.0f);
        float a = tv*f;
        ci[tid]    = sinf(a);
        ci[16+tid] = cosf(a);
    }
    if (tid < 4) ci[32+tid] = conditioning[b*4+tid];
    __syncthreads();
    if (tid < 144){
        float acc = bc1[tid];
        #pragma unroll
        for (int c=0;c<36;c++) acc += ci[c]*Wc1[c*144+tid];
        h1[tid] = gelu_f(acc);
    }
    __syncthreads();
    if (tid < 144){
        float acc = bc2[tid];
        #pragma unroll 36
        for (int c=0;c<144;c++) acc += h1[c]*Wc2[c*144+tid];
        h2[tid] = gelu_f(acc);
    }
    __syncthreads();
    if (tid < 36){
        float acc = bc3[tid];
        #pragma unroll 36
        for (int c=0;c<144;c++) acc += h2[c]*Wc3[c*36+tid];
        cnd[tid] = acc;
    }
    __syncthreads();
    if (tid < 128){
        float accC = be1[tid], s1 = 0.f, s2 = 0.f;
        #pragma unroll
        for (int c=0;c<36;c++){
            float w1 = We1[c*128+tid];
            float w2 = We1[(36+c)*128+tid];
            accC += cnd[c]*(w1+w2);
            s1 += w1; s2 += w2;
        }
        consts[b*128+tid] = accC;
        pack[tid*12 + b] = accC;
        if (b==0){
            consts[256+tid] = s1; consts[384+tid] = s2;
            pack[tid*12+2] = s1;
            pack[tid*12+3] = s2;
            pack[tid*12+4] = We1[72*128+tid];
            pack[tid*12+5] = We1[73*128+tid];
            pack[tid*12+6] = We1[74*128+tid];
            pack[tid*12+7] = We1[75*128+tid];
            pack[tid*12+8]  = We2[tid*4+0];
            pack[tid*12+9]  = We2[tid*4+1];
            pack[tid*12+10] = We2[tid*4+2];
            pack[tid*12+11] = We2[tid*4+3];
        }
    }
    if (tid < 64){
        float accD = bn1[tid], t1 = 0.f;
        #pragma unroll
        for (int c=0;c<36;c++){
            float w = Wn1[c*64+tid];
            accD += cnd[c]*w;
            t1 += w;
        }
        consts[512 + b*64 + tid] = accD;
        if (b==0) consts[640+tid] = t1;
    }
}

// ---------------- K2: fused KNN + select (two-pass), 4 waves x 4 nodes ----------------
// Distance: per-target-shifted d2' = r_j^2 - 2 p_i.p_j (ordering-equivalent per target;
// threshold from same shifted values -> identical selection). 3 FMA + min per candidate.
// 16 nodes/block (256 thr, 4 waves), grid = 1024 = 4 blocks/CU: the machine was
// GRID-limited before (512 blocks = 2/CU, 256 blocks = 1/CU). 4 independent barrier
// domains per CU decorrelate __syncthreads stalls.
// NOTE: prefetch MUST stay in named scalars (pre0..pre3) — array form indexed inside
// the g-loop goes to scratch (rule #20; round-1 regression: 88 MB of HBM writes).
__global__ __launch_bounds__(256, 4) void knn_kernel(const float4* __restrict__ pos4,
                                                     int* __restrict__ nbr){
    __shared__ float4 sPos[GT*64];      // 16 KB
    __shared__ float2 sCand[16*64];     // 8 KB
    int tid = threadIdx.x;
    int w = tid >> 6, lane = tid & 63;
    int n0g = blockIdx.x * 16;
    int b = n0g >> 13;
    int n0 = n0g & (NB-1);
    const float4* __restrict__ P = pos4 + b*NB;

    int nw = n0 + w*4;
    float nx[4], ny[4], nz[4], acc[4];
    #pragma unroll
    for (int k=0;k<4;k++){
        float4 p = P[nw+k];
        nx[k] = -2.0f*p.x; ny[k] = -2.0f*p.y; nz[k] = -2.0f*p.z;
        acc[k] = BIG;
    }
    int selfTile = n0 >> 6;            // all 16 block nodes share one tile
    int sl0 = (n0 & 63) + w*4;         // self lane for node k is sl0+k

    // ---- Pass A ----
    float4 pre0 = P[(w*4    )*64 + lane];
    float4 pre1 = P[(w*4 + 1)*64 + lane];
    float4 pre2 = P[(w*4 + 2)*64 + lane];
    float4 pre3 = P[(w*4 + 3)*64 + lane];
    for (int g=0; g<NG; ++g){
        __syncthreads();
        sPos[(w*4    )*64 + lane] = pre0;
        sPos[(w*4 + 1)*64 + lane] = pre1;
        sPos[(w*4 + 2)*64 + lane] = pre2;
        sPos[(w*4 + 3)*64 + lane] = pre3;
        if (g+1 < NG){
            pre0 = P[((g+1)*GT + w*4    )*64 + lane];
            pre1 = P[((g+1)*GT + w*4 + 1)*64 + lane];
            pre2 = P[((g+1)*GT + w*4 + 2)*64 + lane];
            pre3 = P[((g+1)*GT + w*4 + 3)*64 + lane];
        }
        __syncthreads();
        int tbase = g*GT;
        #pragma unroll
        for (int t=0;t<GT;t++){
            float4 q = sPos[t*64 + lane];
            if (tbase + t != selfTile){
                #pragma unroll
                for (int k=0;k<4;k++){
                    float d2 = fmaf(nx[k],q.x, fmaf(ny[k],q.y, fmaf(nz[k],q.z, q.w)));
                    acc[k] = fminf(acc[k], d2);
                }
            } else {
                #pragma unroll
                for (int k=0;k<4;k++){
                    float d2 = fmaf(nx[k],q.x, fmaf(ny[k],q.y, fmaf(nz[k],q.z, q.w)));
                    if (lane == sl0 + k) d2 = BIG;
                    acc[k] = fminf(acc[k], d2);
                }
            }
        }
    }

    // ---- T[k] = 20th smallest of 64 per-lane minima ----
    float T[4];
    #pragma unroll
    for (int k=0;k<4;k++){
        float v = acc[k];
        #pragma unroll
        for (int K=2; K<=64; K<<=1){
            #pragma unroll
            for (int j=K>>1; j>0; j>>=1){
                float o = __shfl_xor(v, j);
                bool keepmin = (((lane & j) == 0) == ((lane & K) == 0));
                float mn = fminf(v,o), mx = fmaxf(v,o);
                v = keepmin ? mn : mx;
            }
        }
        T[k] = __shfl(v, 19);
    }

    // ---- Pass B: collect into LDS ----
    int cnt[4];
    #pragma unroll
    for (int k=0;k<4;k++) cnt[k] = 0;
    unsigned long long lt = (1ull << lane) - 1ull;

    pre0 = P[(w*4    )*64 + lane];
    pre1 = P[(w*4 + 1)*64 + lane];
    pre2 = P[(w*4 + 2)*64 + lane];
    pre3 = P[(w*4 + 3)*64 + lane];
    for (int g=0; g<NG; ++g){
        __syncthreads();
        sPos[(w*4    )*64 + lane] = pre0;
        sPos[(w*4 + 1)*64 + lane] = pre1;
        sPos[(w*4 + 2)*64 + lane] = pre2;
        sPos[(w*4 + 3)*64 + lane] = pre3;
        if (g+1 < NG){
            pre0 = P[((g+1)*GT + w*4    )*64 + lane];
            pre1 = P[((g+1)*GT + w*4 + 1)*64 + lane];
            pre2 = P[((g+1)*GT + w*4 + 2)*64 + lane];
            pre3 = P[((g+1)*GT + w*4 + 3)*64 + lane];
        }
        __syncthreads();
        int tbase = g*GT;
        #pragma unroll 4
        for (int t=0;t<GT;t++){
            int tile = tbase + t;
            float4 q = sPos[t*64 + lane];
            int j = (tile<<6) + lane;
            bool selft = (tile == selfTile);
            #pragma unroll
            for (int k=0;k<4;k++){
                float d2 = fmaf(nx[k],q.x, fmaf(ny[k],q.y, fmaf(nz[k],q.z, q.w)));
                bool hit = (d2 <= T[k]);
                if (selft && (lane == sl0 + k)) hit = false;
                unsigned long long m = __ballot(hit);
                if (m){
                    if (hit){
                        int off = cnt[k] + (int)__popcll(m & lt);
                        if (off < 64)
                            sCand[(w*4+k)*64 + off] = make_float2(d2, __int_as_float(j));
                    }
                    cnt[k] += (int)__popcll(m);
                }
            }
        }
    }

    // ---- sort each node's candidates (same-wave data; no barrier needed) ----
    #pragma unroll
    for (int k=0;k<4;k++){
        int m = cnt[k]; if (m > 64) m = 64;
        float d; int idx;
        if (lane < m){
            float2 e = sCand[(w*4+k)*64 + lane];
            d = e.x; idx = __float_as_int(e.y);
        } else { d = BIG; idx = 0x7f000000 + lane; }
        #pragma unroll
        for (int K=2; K<=64; K<<=1){
            #pragma unroll
            for (int j=K>>1; j>0; j>>=1){
                float od = __shfl_xor(d, j);
                int   oi = __shfl_xor(idx, j);
                bool pless = (od < d) || (od == d && oi < idx);
                bool keepmin = (((lane & j) == 0) == ((lane & K) == 0));
                if (pless == keepmin){ d = od; idx = oi; }
            }
        }
        if (lane < KNN) nbr[(size_t)(n0g + w*4 + k)*KNN + lane] = idx;
    }
}

// ---------------- K3: fused edge MLP + softmax-aggregate + node MLP + output ----------------
// 1024 blocks x 320 threads; block owns 16 nodes = 320 edges exactly.
__global__ __launch_bounds__(320) void edgenode_kernel(const float4* __restrict__ pos4,
        const float4* __restrict__ vel4,
        const int* __restrict__ nbr,
        const float* __restrict__ pack,
        const float* __restrict__ consts,
        const float* __restrict__ Wn1,
        const float* __restrict__ Wn2,
        const float* __restrict__ be2,
        const float* __restrict__ bn2,
        const float* __restrict__ alpha_p,
        const float* __restrict__ beta_p,
        const float* __restrict__ z,
        float* __restrict__ out){
    __shared__ float4 sP[384];                       // 6 KB edge weights
    __shared__ float sLg[320], sSm[320], sUx[320], sUy[320], sUz[320];  // 6.25 KB
    __shared__ float sD[64], sT1[64], sW36[64], sWo[64];
    __shared__ float sMf[16];
    __shared__ float4 sAgg[16];                      // {vax,vay,vaz,sagg}
    __shared__ float sPart[320];

    int tid = threadIdx.x;
    bool bb = (blockIdx.x >= 512);                   // batch block-uniform
    for (int k=tid; k<384; k+=320) sP[k] = ((const float4*)pack)[k];
    if (tid < 64){
        sD[tid]   = consts[512 + (bb?64:0) + tid];
        sT1[tid]  = consts[640+tid];
        sW36[tid] = Wn1[36*64+tid];
        sWo[tid]  = Wn2[tid];
    }

    int e = blockIdx.x*320 + tid;
    int i = e / KNN;                   // global tgt node
    int ln = tid / KNN;                // local node 0..15
    int r  = tid - ln*KNN;             // edge rank 0..19
    int bbase = bb ? NB : 0;
    int s = nbr[e];
    float4 ps = pos4[bbase + s], pt = pos4[i];
    float4 vs = vel4[bbase + s], vt = vel4[i];
    if (r == 0) sMf[ln] = vt.w;

    float rx = ps.x - pt.x, ry = ps.y - pt.y, rz = ps.z - pt.z;
    float r2  = rx*rx + ry*ry + rz*rz;
    float vv  = vs.x*vt.x + vs.y*vt.y + vs.z*vt.z;
    float vsr = vs.x*rx + vs.y*ry + vs.z*rz;
    float vtr = vt.x*rx + vt.y*ry + vt.z*rz;
    float mfs = vs.w, mft = vt.w;
    __syncthreads();   // sP ready

    float a0 = be2[0], a1 = be2[1], a2 = be2[2], a3 = be2[3];
    #pragma unroll 4
    for (int h=0; h<128; h++){
        float4 A  = sP[h*3];
        float4 Bv = sP[h*3+1];
        float4 C  = sP[h*3+2];
        float base = bb ? A.y : A.x;
        float x = base + mfs*A.z + mft*A.w + r2*Bv.x + vv*Bv.y + vsr*Bv.z + vtr*Bv.w;
        float gx = gelu_f(x);
        a0 += gx*C.x; a1 += gx*C.y; a2 += gx*C.z; a3 += gx*C.w;
    }
    sLg[tid] = a0;
    sSm[tid] = a1;
    sUx[tid] = a2*rx + a3*vs.x;
    sUy[tid] = a2*ry + a3*vs.y;
    sUz[tid] = a2*rz + a3*vs.z;
    __syncthreads();

    // per-node softmax + aggregation (16 serial lanes)
    if (tid < 16){
        int base = tid*KNN;
        float m = -BIG;
        #pragma unroll
        for (int q=0;q<KNN;q++) m = fmaxf(m, sLg[base+q]);
        float den=0.f, wx=0.f, wy=0.f, wz=0.f, wsm=0.f;
        #pragma unroll
        for (int q=0;q<KNN;q++){
            float a = __expf(sLg[base+q]-m);
            den += a;
            wsm += a*sSm[base+q];
            wx  += a*sUx[base+q];
            wy  += a*sUy[base+q];
            wz  += a*sUz[base+q];
        }
        float inv = __fdividef(1.0f, den);
        sAgg[tid] = make_float4(wx*inv, wy*inv, wz*inv, wsm*inv);
    }
    __syncthreads();

    // node MLP partials: 20 threads per node, h = r, r+20, r+40, (r+60)
    {
        float mf = sMf[ln];
        float sg = sAgg[ln].w;
        float part = 0.f;
        #pragma unroll
        for (int h=r; h<64; h+=KNN){
            float x = sD[h] + mf*sT1[h] + sg*sW36[h];
            part += gelu_f(x)*sWo[h];
        }
        sPart[tid] = part;
    }
    __syncthreads();

    if (tid < 16){
        float sout = bn2[0];
        #pragma unroll
        for (int q=0;q<KNN;q++) sout += sPart[tid*KNN+q];
        int node = blockIdx.x*16 + tid;
        float alpha = alpha_p[0], beta = beta_p[0];
        float4 ag = sAgg[tid];
        const float* zp = z + (size_t)node*7;
        float* op = out + (size_t)node*7;
        op[0] = zp[0]*2.0f + alpha*ag.x;
        op[1] = zp[1]*2.0f + alpha*ag.y;
        op[2] = zp[2]*2.0f + alpha*ag.z;
        op[3] = zp[3] + beta*ag.x;
        op[4] = zp[4] + beta*ag.y;
        op[5] = zp[5] + beta*ag.z;
        op[6] = zp[6] + sout;
    }
}

extern "C" void kernel_launch(void* const* d_in, const int* in_sizes, int n_in,
                              void* d_out, int out_size, void* d_ws, size_t ws_size,
                              hipStream_t stream) {
    const float* z    = (const float*)d_in[0];
    const float* t    = (const float*)d_in[1];
    const float* cond = (const float*)d_in[2];
    const float* Wc1  = (const float*)d_in[4];
    const float* bc1  = (const float*)d_in[5];
    const float* Wc2  = (const float*)d_in[6];
    const float* bc2  = (const float*)d_in[7];
    const float* Wc3  = (const float*)d_in[8];
    const float* bc3  = (const float*)d_in[9];
    const float* We1  = (const float*)d_in[10];
    const float* be1  = (const float*)d_in[11];
    const float* We2  = (const float*)d_in[12];
    const float* be2  = (const float*)d_in[13];
    const float* Wn1  = (const float*)d_in[14];
    const float* bn1  = (const float*)d_in[15];
    const float* Wn2  = (const float*)d_in[16];
    const float* bn2  = (const float*)d_in[17];
    const float* alp  = (const float*)d_in[18];
    const float* bet  = (const float*)d_in[19];
    float* out = (float*)d_out;

    char* ws = (char*)d_ws;
    float4* pos4   = (float4*)(ws);                      // 262144 B
    float4* vel4   = (float4*)(ws + 262144);             // 262144 B
    float*  consts = (float*)(ws + 524288);              // 4096 B
    float*  pack   = (float*)(ws + 528384);              // 6144 B
    int*    nbr    = (int*)(ws + 534528);                // 1310720 B

    prepcond_kernel<<<dim3(BN/256), dim3(256), 0, stream>>>(z, t, cond,
        Wc1, bc1, Wc2, bc2, Wc3, bc3, We1, be1, We2, Wn1, bn1,
        pos4, vel4, consts, pack);
    knn_kernel<<<dim3(BN/16), dim3(256), 0, stream>>>(pos4, nbr);
    edgenode_kernel<<<dim3(BN/16), dim3(320), 0, stream>>>(pos4, vel4, nbr, pack, consts,
        Wn1, Wn2, be2, bn2, alp, bet, z, out);
}

// Round 5
// 205.238 us; speedup vs baseline: 1.1473x; 1.0111x over previous
//
#include <hip/hip_runtime.h>
#include <math.h>

#define NB 8192
#define BATCH 2
#define KNN 20
#define BN (BATCH*NB)
#define NE (BN*KNN)        // 327680 edges
#define GT 16              // tiles per staged group (16 KB)
#define NG 8               // groups per pass
#define BIG 3.0e38f

// gelu(x) = 0.5x(1+tanh(a)), a = 0.79788456*(x+0.044715x^3)
//         = x * sigmoid(2a) = x / (1 + exp(-2a));  -2a = x*(-1.5957691 - 0.07135482*x^2)
__device__ __forceinline__ float gelu_f(float x){
    float t = x*x;
    float m = x*fmaf(t, -0.0713548163f, -1.5957691216f);
    float e = __expf(m);
    return __fdividef(x, 1.0f + e);
}

// ---------------- K1: prep (all 64 blocks) + cond MLP (blocks 0,1) ----------------
// consts floats: C[2][128]@0, S1[128]@256, S2[128]@384, D[2][64]@512, T1[64]@640
// pack per h (128): {C0,C1,S1,S2, W72,W73,W74,W75, V0,V1,V2,V3} = 12 floats
__global__ __launch_bounds__(256) void prepcond_kernel(const float* __restrict__ z,
        const float* __restrict__ t,
        const float* __restrict__ conditioning,
        const float* __restrict__ Wc1, const float* __restrict__ bc1,
        const float* __restrict__ Wc2, const float* __restrict__ bc2,
        const float* __restrict__ Wc3, const float* __restrict__ bc3,
        const float* __restrict__ We1, const float* __restrict__ be1,
        const float* __restrict__ We2,
        const float* __restrict__ Wn1, const float* __restrict__ bn1,
        float4* __restrict__ pos4, float4* __restrict__ vel4,
        float* __restrict__ consts, float* __restrict__ pack){
    int tid = threadIdx.x;
    int g = blockIdx.x*256 + tid;
    const float* zp = z + (size_t)g*7;
    float x = zp[0], y = zp[1], zz = zp[2];
    float r2 = x*x + y*y + zz*zz;
    pos4[g] = make_float4(x, y, zz, r2);
    vel4[g] = make_float4(zp[3], zp[4], zp[5], zp[6]);

    if (blockIdx.x >= BATCH) return;
    int b = blockIdx.x;
    __shared__ float ci[36];
    __shared__ float h1[144];
    __shared__ float h2[144];
    __shared__ float cnd[36];
    float tv = t[b];
    if (tid < 16){
        float f = expf(-9.210340371976184f * (float)tid / 15.0f);
        float a = tv*f;
        ci[tid]    = sinf(a);
        ci[16+tid] = cosf(a);
    }
    if (tid < 4) ci[32+tid] = conditioning[b*4+tid];
    __syncthreads();
    if (tid < 144){
        float acc = bc1[tid];
        #pragma unroll
        for (int c=0;c<36;c++) acc += ci[c]*Wc1[c*144+tid];
        h1[tid] = gelu_f(acc);
    }
    __syncthreads();
    if (tid < 144){
        float acc = bc2[tid];
        #pragma unroll 36
        for (int c=0;c<144;c++) acc += h1[c]*Wc2[c*144+tid];
        h2[tid] = gelu_f(acc);
    }
    __syncthreads();
    if (tid < 36){
        float acc = bc3[tid];
        #pragma unroll 36
        for (int c=0;c<144;c++) acc += h2[c]*Wc3[c*36+tid];
        cnd[tid] = acc;
    }
    __syncthreads();
    if (tid < 128){
        float accC = be1[tid], s1 = 0.f, s2 = 0.f;
        #pragma unroll
        for (int c=0;c<36;c++){
            float w1 = We1[c*128+tid];
            float w2 = We1[(36+c)*128+tid];
            accC += cnd[c]*(w1+w2);
            s1 += w1; s2 += w2;
        }
        consts[b*128+tid] = accC;
        pack[tid*12 + b] = accC;
        if (b==0){
            consts[256+tid] = s1; consts[384+tid] = s2;
            pack[tid*12+2] = s1;
            pack[tid*12+3] = s2;
            pack[tid*12+4] = We1[72*128+tid];
            pack[tid*12+5] = We1[73*128+tid];
            pack[tid*12+6] = We1[74*128+tid];
            pack[tid*12+7] = We1[75*128+tid];
            pack[tid*12+8]  = We2[tid*4+0];
            pack[tid*12+9]  = We2[tid*4+1];
            pack[tid*12+10] = We2[tid*4+2];
            pack[tid*12+11] = We2[tid*4+3];
        }
    }
    if (tid < 64){
        float accD = bn1[tid], t1 = 0.f;
        #pragma unroll
        for (int c=0;c<36;c++){
            float w = Wn1[c*64+tid];
            accD += cnd[c]*w;
            t1 += w;
        }
        consts[512 + b*64 + tid] = accD;
        if (b==0) consts[640+tid] = t1;
    }
}

// ---------------- K2: fused KNN + select (proven two-pass), 8 waves x 4 nodes ----------------
// R2-proven config (67 us): 512 thr, 4 nodes/wave, grid BN/32. Do not restructure:
// - prefetch stays in named scalars (pre0/pre1): array form -> scratch (rule #20, R1: 88MB writes)
// - 8-node amortization (R3) and 4x256thr blocks (R4) both regressed; occupancy plateau
//   ~12 waves/CU is not barrier-domain-limited.
// Distance: per-target-shifted d2' = r_j^2 - 2 p_i.p_j (ordering-equivalent; threshold from
// same shifted values -> identical selection). Self excluded explicitly.
__global__ __launch_bounds__(512, 4) void knn_kernel(const float4* __restrict__ pos4,
                                                     int* __restrict__ nbr){
    __shared__ float4 sPos[GT*64];      // 16 KB
    __shared__ float2 sCand[32*64];     // 16 KB
    int tid = threadIdx.x;
    int w = tid >> 6, lane = tid & 63;
    int n0g = blockIdx.x * 32;
    int b = n0g >> 13;
    int n0 = n0g & (NB-1);
    const float4* __restrict__ P = pos4 + b*NB;

    int nw = n0 + w*4;
    float nx[4], ny[4], nz[4], acc[4];
    #pragma unroll
    for (int k=0;k<4;k++){
        float4 p = P[nw+k];
        nx[k] = -2.0f*p.x; ny[k] = -2.0f*p.y; nz[k] = -2.0f*p.z;
        acc[k] = BIG;
    }
    int selfTile = n0 >> 6;            // all 32 block nodes share one tile
    int sl0 = (n0 & 63) + w*4;         // self lane for node k is sl0+k

    // ---- Pass A ----
    float4 pre0 = P[(w*2    )*64 + lane];
    float4 pre1 = P[(w*2 + 1)*64 + lane];
    for (int g=0; g<NG; ++g){
        __syncthreads();
        sPos[(w*2    )*64 + lane] = pre0;
        sPos[(w*2 + 1)*64 + lane] = pre1;
        if (g+1 < NG){
            pre0 = P[((g+1)*GT + w*2    )*64 + lane];
            pre1 = P[((g+1)*GT + w*2 + 1)*64 + lane];
        }
        __syncthreads();
        int tbase = g*GT;
        #pragma unroll
        for (int t=0;t<GT;t++){
            float4 q = sPos[t*64 + lane];
            if (tbase + t != selfTile){
                #pragma unroll
                for (int k=0;k<4;k++){
                    float d2 = fmaf(nx[k],q.x, fmaf(ny[k],q.y, fmaf(nz[k],q.z, q.w)));
                    acc[k] = fminf(acc[k], d2);
                }
            } else {
                #pragma unroll
                for (int k=0;k<4;k++){
                    float d2 = fmaf(nx[k],q.x, fmaf(ny[k],q.y, fmaf(nz[k],q.z, q.w)));
                    if (lane == sl0 + k) d2 = BIG;
                    acc[k] = fminf(acc[k], d2);
                }
            }
        }
    }

    // ---- T[k] = 20th smallest of 64 per-lane minima ----
    float T[4];
    #pragma unroll
    for (int k=0;k<4;k++){
        float v = acc[k];
        #pragma unroll
        for (int K=2; K<=64; K<<=1){
            #pragma unroll
            for (int j=K>>1; j>0; j>>=1){
                float o = __shfl_xor(v, j);
                bool keepmin = (((lane & j) == 0) == ((lane & K) == 0));
                float mn = fminf(v,o), mx = fmaxf(v,o);
                v = keepmin ? mn : mx;
            }
        }
        T[k] = __shfl(v, 19);
    }

    // ---- Pass B: collect into LDS ----
    int cnt[4];
    #pragma unroll
    for (int k=0;k<4;k++) cnt[k] = 0;
    unsigned long long lt = (1ull << lane) - 1ull;

    pre0 = P[(w*2    )*64 + lane];
    pre1 = P[(w*2 + 1)*64 + lane];
    for (int g=0; g<NG; ++g){
        __syncthreads();
        sPos[(w*2    )*64 + lane] = pre0;
        sPos[(w*2 + 1)*64 + lane] = pre1;
        if (g+1 < NG){
            pre0 = P[((g+1)*GT + w*2    )*64 + lane];
            pre1 = P[((g+1)*GT + w*2 + 1)*64 + lane];
        }
        __syncthreads();
        int tbase = g*GT;
        #pragma unroll 4
        for (int t=0;t<GT;t++){
            int tile = tbase + t;
            float4 q = sPos[t*64 + lane];
            int j = (tile<<6) + lane;
            bool selft = (tile == selfTile);
            #pragma unroll
            for (int k=0;k<4;k++){
                float d2 = fmaf(nx[k],q.x, fmaf(ny[k],q.y, fmaf(nz[k],q.z, q.w)));
                bool hit = (d2 <= T[k]);
                if (selft && (lane == sl0 + k)) hit = false;
                unsigned long long m = __ballot(hit);
                if (m){
                    if (hit){
                        int off = cnt[k] + (int)__popcll(m & lt);
                        if (off < 64)
                            sCand[(w*4+k)*64 + off] = make_float2(d2, __int_as_float(j));
                    }
                    cnt[k] += (int)__popcll(m);
                }
            }
        }
    }

    // ---- sort each node's candidates (same-wave data; no barrier needed) ----
    #pragma unroll
    for (int k=0;k<4;k++){
        int m = cnt[k]; if (m > 64) m = 64;
        float d; int idx;
        if (lane < m){
            float2 e = sCand[(w*4+k)*64 + lane];
            d = e.x; idx = __float_as_int(e.y);
        } else { d = BIG; idx = 0x7f000000 + lane; }
        #pragma unroll
        for (int K=2; K<=64; K<<=1){
            #pragma unroll
            for (int j=K>>1; j>0; j>>=1){
                float od = __shfl_xor(d, j);
                int   oi = __shfl_xor(idx, j);
                bool pless = (od < d) || (od == d && oi < idx);
                bool keepmin = (((lane & j) == 0) == ((lane & K) == 0));
                if (pless == keepmin){ d = od; idx = oi; }
            }
        }
        if (lane < KNN) nbr[(size_t)(n0g + w*4 + k)*KNN + lane] = idx;
    }
}

// ---------------- K3: fused edge MLP + softmax-aggregate + node MLP + output ----------------
// 512 blocks x 320 threads; block owns 32 nodes = 640 edges; EACH THREAD OWNS 2 EDGES
// (e0 = base+tid, e1 = e0+320). Each broadcast ds_read of the weight triple now serves
// 2 edges -> LDS reads per edge halved (the h-loop was LDS-pipe-bound: 384 b128/wave
// serving only 64 edges). All per-edge state in named scalars (rule #20).
__global__ __launch_bounds__(320) void edgenode_kernel(const float4* __restrict__ pos4,
        const float4* __restrict__ vel4,
        const int* __restrict__ nbr,
        const float* __restrict__ pack,
        const float* __restrict__ consts,
        const float* __restrict__ Wn1,
        const float* __restrict__ Wn2,
        const float* __restrict__ be2,
        const float* __restrict__ bn2,
        const float* __restrict__ alpha_p,
        const float* __restrict__ beta_p,
        const float* __restrict__ z,
        float* __restrict__ out){
    __shared__ float4 sP[384];                       // 6 KB edge weights
    __shared__ float sLg[640], sSm[640], sUx[640], sUy[640], sUz[640];  // 12.5 KB
    __shared__ float sD[64], sT1[64], sW36[64], sWo[64];
    __shared__ float sMf[32];
    __shared__ float4 sAgg[32];                      // {vax,vay,vaz,sagg}
    __shared__ float sPart[640];

    int tid = threadIdx.x;
    bool bb = (blockIdx.x >= 256);                   // batch block-uniform
    for (int k=tid; k<384; k+=320) sP[k] = ((const float4*)pack)[k];
    if (tid < 64){
        sD[tid]   = consts[512 + (bb?64:0) + tid];
        sT1[tid]  = consts[640+tid];
        sW36[tid] = Wn1[36*64+tid];
        sWo[tid]  = Wn2[tid];
    }

    int e0 = blockIdx.x*640 + tid;
    int e1 = e0 + 320;
    int i0 = e0 / KNN;                 // global tgt node (edge 0)
    int i1 = i0 + 16;                  // edge 1 targets node +16 (320/20 nodes later)
    int ln0 = tid / KNN;               // local node 0..15
    int r  = tid - ln0*KNN;            // edge rank 0..19 (same for both edges)
    int bbase = bb ? NB : 0;
    int s0 = nbr[e0], s1 = nbr[e1];
    float4 ps0 = pos4[bbase + s0], pt0 = pos4[i0];
    float4 vs0 = vel4[bbase + s0], vt0 = vel4[i0];
    float4 ps1 = pos4[bbase + s1], pt1 = pos4[i1];
    float4 vs1 = vel4[bbase + s1], vt1 = vel4[i1];
    if (r == 0){ sMf[ln0] = vt0.w; sMf[ln0+16] = vt1.w; }

    float rx0 = ps0.x - pt0.x, ry0 = ps0.y - pt0.y, rz0 = ps0.z - pt0.z;
    float r20  = rx0*rx0 + ry0*ry0 + rz0*rz0;
    float vv0  = vs0.x*vt0.x + vs0.y*vt0.y + vs0.z*vt0.z;
    float vsr0 = vs0.x*rx0 + vs0.y*ry0 + vs0.z*rz0;
    float vtr0 = vt0.x*rx0 + vt0.y*ry0 + vt0.z*rz0;
    float mfs0 = vs0.w, mft0 = vt0.w;

    float rx1 = ps1.x - pt1.x, ry1 = ps1.y - pt1.y, rz1 = ps1.z - pt1.z;
    float r21  = rx1*rx1 + ry1*ry1 + rz1*rz1;
    float vv1  = vs1.x*vt1.x + vs1.y*vt1.y + vs1.z*vt1.z;
    float vsr1 = vs1.x*rx1 + vs1.y*ry1 + vs1.z*rz1;
    float vtr1 = vt1.x*rx1 + vt1.y*ry1 + vt1.z*rz1;
    float mfs1 = vs1.w, mft1 = vt1.w;
    __syncthreads();   // sP ready

    float a00 = be2[0], a10 = be2[1], a20 = be2[2], a30 = be2[3];
    float a01 = a00, a11 = a10, a21 = a20, a31 = a30;
    #pragma unroll 2
    for (int h=0; h<128; h++){
        float4 A  = sP[h*3];
        float4 Bv = sP[h*3+1];
        float4 C  = sP[h*3+2];
        float base = bb ? A.y : A.x;
        float x0 = base + mfs0*A.z + mft0*A.w + r20*Bv.x + vv0*Bv.y + vsr0*Bv.z + vtr0*Bv.w;
        float x1 = base + mfs1*A.z + mft1*A.w + r21*Bv.x + vv1*Bv.y + vsr1*Bv.z + vtr1*Bv.w;
        float g0 = gelu_f(x0);
        float g1 = gelu_f(x1);
        a00 += g0*C.x; a10 += g0*C.y; a20 += g0*C.z; a30 += g0*C.w;
        a01 += g1*C.x; a11 += g1*C.y; a21 += g1*C.z; a31 += g1*C.w;
    }
    sLg[tid]     = a00;  sLg[tid+320] = a01;
    sSm[tid]     = a10;  sSm[tid+320] = a11;
    sUx[tid]     = a20*rx0 + a30*vs0.x;  sUx[tid+320] = a21*rx1 + a31*vs1.x;
    sUy[tid]     = a20*ry0 + a30*vs0.y;  sUy[tid+320] = a21*ry1 + a31*vs1.y;
    sUz[tid]     = a20*rz0 + a30*vs0.z;  sUz[tid+320] = a21*rz1 + a31*vs1.z;
    __syncthreads();

    // per-node softmax + aggregation (32 serial lanes)
    if (tid < 32){
        int base = tid*KNN;
        float m = -BIG;
        #pragma unroll
        for (int q=0;q<KNN;q++) m = fmaxf(m, sLg[base+q]);
        float den=0.f, wx=0.f, wy=0.f, wz=0.f, wsm=0.f;
        #pragma unroll
        for (int q=0;q<KNN;q++){
            float a = __expf(sLg[base+q]-m);
            den += a;
            wsm += a*sSm[base+q];
            wx  += a*sUx[base+q];
            wy  += a*sUy[base+q];
            wz  += a*sUz[base+q];
        }
        float inv = __fdividef(1.0f, den);
        sAgg[tid] = make_float4(wx*inv, wy*inv, wz*inv, wsm*inv);
    }
    __syncthreads();

    // node MLP partials: 20 threads per node, h = r, r+20, r+40, (r+60); two nodes/thread
    {
        float mf0 = sMf[ln0],     sg0 = sAgg[ln0].w;
        float mf1 = sMf[ln0+16],  sg1 = sAgg[ln0+16].w;
        float p0 = 0.f, p1 = 0.f;
        #pragma unroll
        for (int h=r; h<64; h+=KNN){
            float x0 = sD[h] + mf0*sT1[h] + sg0*sW36[h];
            float x1 = sD[h] + mf1*sT1[h] + sg1*sW36[h];
            p0 += gelu_f(x0)*sWo[h];
            p1 += gelu_f(x1)*sWo[h];
        }
        sPart[tid]     = p0;
        sPart[tid+320] = p1;
    }
    __syncthreads();

    if (tid < 32){
        float sout = bn2[0];
        #pragma unroll
        for (int q=0;q<KNN;q++) sout += sPart[tid*KNN+q];
        int node = blockIdx.x*32 + tid;
        float alpha = alpha_p[0], beta = beta_p[0];
        float4 ag = sAgg[tid];
        const float* zp = z + (size_t)node*7;
        float* op = out + (size_t)node*7;
        op[0] = zp[0]*2.0f + alpha*ag.x;
        op[1] = zp[1]*2.0f + alpha*ag.y;
        op[2] = zp[2]*2.0f + alpha*ag.z;
        op[3] = zp[3] + beta*ag.x;
        op[4] = zp[4] + beta*ag.y;
        op[5] = zp[5] + beta*ag.z;
        op[6] = zp[6] + sout;
    }
}

extern "C" void kernel_launch(void* const* d_in, const int* in_sizes, int n_in,
                              void* d_out, int out_size, void* d_ws, size_t ws_size,
                              hipStream_t stream) {
    const float* z    = (const float*)d_in[0];
    const float* t    = (const float*)d_in[1];
    const float* cond = (const float*)d_in[2];
    const float* Wc1  = (const float*)d_in[4];
    const float* bc1  = (const float*)d_in[5];
    const float* Wc2  = (const float*)d_in[6];
    const float* bc2  = (const float*)d_in[7];
    const float* Wc3  = (const float*)d_in[8];
    const float* bc3  = (const float*)d_in[9];
    const float* We1  = (const float*)d_in[10];
    const float* be1  = (const float*)d_in[11];
    const float* We2  = (const float*)d_in[12];
    const float* be2  = (const float*)d_in[13];
    const float* Wn1  = (const float*)d_in[14];
    const float* bn1  = (const float*)d_in[15];
    const float* Wn2  = (const float*)d_in[16];
    const float* bn2  = (const float*)d_in[17];
    const float* alp  = (const float*)d_in[18];
    const float* bet  = (const float*)d_in[19];
    float* out = (float*)d_out;

    char* ws = (char*)d_ws;
    float4* pos4   = (float4*)(ws);                      // 262144 B
    float4* vel4   = (float4*)(ws + 262144);             // 262144 B
    float*  consts = (float*)(ws + 524288);              // 4096 B
    float*  pack   = (float*)(ws + 528384);              // 6144 B
    int*    nbr    = (int*)(ws + 534528);                // 1310720 B

    prepcond_kernel<<<dim3(BN/256), dim3(256), 0, stream>>>(z, t, cond,
        Wc1, bc1, Wc2, bc2, Wc3, bc3, We1, be1, We2, Wn1, bn1,
        pos4, vel4, consts, pack);
    knn_kernel<<<dim3(BN/32), dim3(512), 0, stream>>>(pos4, nbr);
    edgenode_kernel<<<dim3(NE/640), dim3(320), 0, stream>>>(pos4, vel4, nbr, pack, consts,
        Wn1, Wn2, be2, bn2, alp, bet, z, out);
}

// Round 6
// 202.825 us; speedup vs baseline: 1.1610x; 1.0119x over previous
//
#include <hip/hip_runtime.h>
#include <math.h>

#define NB 8192
#define BATCH 2
#define KNN 20
#define BN (BATCH*NB)
#define NE (BN*KNN)        // 327680 edges
#define GT 32              // tiles per staged group (32 KB)
#define NG 4               // groups per pass (8 barrier pairs/pass, was 16)
#define BIG 3.0e38f

typedef float f32x2 __attribute__((ext_vector_type(2)));

// gelu(x) = x * sigmoid(2a) = x / (1 + exp(-2a));  -2a = x*(-1.5957691 - 0.07135482*x^2)
__device__ __forceinline__ float gelu_f(float x){
    float t = x*x;
    float m = x*fmaf(t, -0.0713548163f, -1.5957691216f);
    float e = __expf(m);
    return __fdividef(x, 1.0f + e);
}

// ---------------- K1: prep (all 64 blocks) + cond MLP (blocks 0,1) ----------------
// consts floats: C[2][128]@0, S1[128]@256, S2[128]@384, D[2][64]@512, T1[64]@640
// pack per h (128): {C0,C1,S1,S2, W72,W73,W74,W75, V0,V1,V2,V3} = 12 floats
__global__ __launch_bounds__(256) void prepcond_kernel(const float* __restrict__ z,
        const float* __restrict__ t,
        const float* __restrict__ conditioning,
        const float* __restrict__ Wc1, const float* __restrict__ bc1,
        const float* __restrict__ Wc2, const float* __restrict__ bc2,
        const float* __restrict__ Wc3, const float* __restrict__ bc3,
        const float* __restrict__ We1, const float* __restrict__ be1,
        const float* __restrict__ We2,
        const float* __restrict__ Wn1, const float* __restrict__ bn1,
        float4* __restrict__ pos4, float4* __restrict__ vel4,
        float* __restrict__ consts, float* __restrict__ pack){
    int tid = threadIdx.x;
    int g = blockIdx.x*256 + tid;
    const float* zp = z + (size_t)g*7;
    float x = zp[0], y = zp[1], zz = zp[2];
    float r2 = x*x + y*y + zz*zz;
    pos4[g] = make_float4(x, y, zz, r2);
    vel4[g] = make_float4(zp[3], zp[4], zp[5], zp[6]);

    if (blockIdx.x >= BATCH) return;
    int b = blockIdx.x;
    __shared__ float ci[36];
    __shared__ float h1[144];
    __shared__ float h2[144];
    __shared__ float cnd[36];
    float tv = t[b];
    if (tid < 16){
        float f = expf(-9.210340371976184f * (float)tid / 15.0f);
        float a = tv*f;
        ci[tid]    = sinf(a);
        ci[16+tid] = cosf(a);
    }
    if (tid < 4) ci[32+tid] = conditioning[b*4+tid];
    __syncthreads();
    if (tid < 144){
        float acc = bc1[tid];
        #pragma unroll
        for (int c=0;c<36;c++) acc += ci[c]*Wc1[c*144+tid];
        h1[tid] = gelu_f(acc);
    }
    __syncthreads();
    if (tid < 144){
        float acc = bc2[tid];
        #pragma unroll 36
        for (int c=0;c<144;c++) acc += h1[c]*Wc2[c*144+tid];
        h2[tid] = gelu_f(acc);
    }
    __syncthreads();
    if (tid < 36){
        float acc = bc3[tid];
        #pragma unroll 36
        for (int c=0;c<144;c++) acc += h2[c]*Wc3[c*36+tid];
        cnd[tid] = acc;
    }
    __syncthreads();
    if (tid < 128){
        float accC = be1[tid], s1 = 0.f, s2 = 0.f;
        #pragma unroll
        for (int c=0;c<36;c++){
            float w1 = We1[c*128+tid];
            float w2 = We1[(36+c)*128+tid];
            accC += cnd[c]*(w1+w2);
            s1 += w1; s2 += w2;
        }
        consts[b*128+tid] = accC;
        pack[tid*12 + b] = accC;
        if (b==0){
            consts[256+tid] = s1; consts[384+tid] = s2;
            pack[tid*12+2] = s1;
            pack[tid*12+3] = s2;
            pack[tid*12+4] = We1[72*128+tid];
            pack[tid*12+5] = We1[73*128+tid];
            pack[tid*12+6] = We1[74*128+tid];
            pack[tid*12+7] = We1[75*128+tid];
            pack[tid*12+8]  = We2[tid*4+0];
            pack[tid*12+9]  = We2[tid*4+1];
            pack[tid*12+10] = We2[tid*4+2];
            pack[tid*12+11] = We2[tid*4+3];
        }
    }
    if (tid < 64){
        float accD = bn1[tid], t1 = 0.f;
        #pragma unroll
        for (int c=0;c<36;c++){
            float w = Wn1[c*64+tid];
            accD += cnd[c]*w;
            t1 += w;
        }
        consts[512 + b*64 + tid] = accD;
        if (b==0) consts[640+tid] = t1;
    }
}

// ---------------- K2: fused KNN + select (two-pass), 8 waves x 4 nodes ----------------
// Distance: per-target-shifted d2' = r_j^2 - 2 p_i.p_j, PACKED over node pairs as
// f32x2 vector mul/add (contracts to v_pk_fma_f32 on CDNA if available; scalarizes to the
// previous fmaf chain otherwise). Both passes use the same DIST4 macro; the threshold is
// bumped by ~16 ulps so pass-B collection stays a superset under any ulp-level codegen
// divergence (extra candidates are removed by the final top-20 sort; selection unchanged).
// GT=32/NG=4 halves barrier pairs per pass. Prefetch in named scalars (rule #20).
#define DIST4(q) \
    f32x2 d01 = nx01*(q).x + (ny01*(q).y + (nz01*(q).z + (q).w)); \
    f32x2 d23 = nx23*(q).x + (ny23*(q).y + (nz23*(q).z + (q).w));

__global__ __launch_bounds__(512, 4) void knn_kernel(const float4* __restrict__ pos4,
                                                     int* __restrict__ nbr){
    __shared__ float4 sPos[GT*64];      // 32 KB
    __shared__ float2 sCand[32*64];     // 16 KB
    int tid = threadIdx.x;
    int w = tid >> 6, lane = tid & 63;
    int n0g = blockIdx.x * 32;
    int b = n0g >> 13;
    int n0 = n0g & (NB-1);
    const float4* __restrict__ P = pos4 + b*NB;

    int nw = n0 + w*4;
    float4 p0 = P[nw], p1 = P[nw+1], p2 = P[nw+2], p3 = P[nw+3];
    f32x2 nx01 = { -2.0f*p0.x, -2.0f*p1.x };
    f32x2 ny01 = { -2.0f*p0.y, -2.0f*p1.y };
    f32x2 nz01 = { -2.0f*p0.z, -2.0f*p1.z };
    f32x2 nx23 = { -2.0f*p2.x, -2.0f*p3.x };
    f32x2 ny23 = { -2.0f*p2.y, -2.0f*p3.y };
    f32x2 nz23 = { -2.0f*p2.z, -2.0f*p3.z };
    f32x2 acc01 = { BIG, BIG }, acc23 = { BIG, BIG };

    int selfTile = n0 >> 6;            // all 32 block nodes share one tile
    int sl0 = (n0 & 63) + w*4;         // self lane for node k is sl0+k

    // ---- Pass A ----
    float4 pre0 = P[(w*4    )*64 + lane];
    float4 pre1 = P[(w*4 + 1)*64 + lane];
    float4 pre2 = P[(w*4 + 2)*64 + lane];
    float4 pre3 = P[(w*4 + 3)*64 + lane];
    for (int g=0; g<NG; ++g){
        __syncthreads();
        sPos[(w*4    )*64 + lane] = pre0;
        sPos[(w*4 + 1)*64 + lane] = pre1;
        sPos[(w*4 + 2)*64 + lane] = pre2;
        sPos[(w*4 + 3)*64 + lane] = pre3;
        if (g+1 < NG){
            pre0 = P[((g+1)*GT + w*4    )*64 + lane];
            pre1 = P[((g+1)*GT + w*4 + 1)*64 + lane];
            pre2 = P[((g+1)*GT + w*4 + 2)*64 + lane];
            pre3 = P[((g+1)*GT + w*4 + 3)*64 + lane];
        }
        __syncthreads();
        int tbase = g*GT;
        #pragma unroll
        for (int t=0;t<GT;t++){
            float4 q = sPos[t*64 + lane];
            DIST4(q)
            if (tbase + t == selfTile){
                if (lane == sl0    ) d01.x = BIG;
                if (lane == sl0 + 1) d01.y = BIG;
                if (lane == sl0 + 2) d23.x = BIG;
                if (lane == sl0 + 3) d23.y = BIG;
            }
            acc01.x = fminf(acc01.x, d01.x); acc01.y = fminf(acc01.y, d01.y);
            acc23.x = fminf(acc23.x, d23.x); acc23.y = fminf(acc23.y, d23.y);
        }
    }

    // ---- T[k] = 20th smallest of 64 per-lane minima, + ulp-scale safety bump ----
    float accs[4] = { acc01.x, acc01.y, acc23.x, acc23.y };
    float T[4];
    #pragma unroll
    for (int k=0;k<4;k++){
        float v = accs[k];
        #pragma unroll
        for (int K=2; K<=64; K<<=1){
            #pragma unroll
            for (int j=K>>1; j>0; j>>=1){
                float o = __shfl_xor(v, j);
                bool keepmin = (((lane & j) == 0) == ((lane & K) == 0));
                float mn = fminf(v,o), mx = fmaxf(v,o);
                v = keepmin ? mn : mx;
            }
        }
        float t20 = __shfl(v, 19);
        T[k] = t20 + fmaxf(fabsf(t20), 1.0f) * 4.0e-6f;
    }

    // ---- Pass B: collect into LDS ----
    int cnt[4];
    #pragma unroll
    for (int k=0;k<4;k++) cnt[k] = 0;
    unsigned long long lt = (1ull << lane) - 1ull;

    pre0 = P[(w*4    )*64 + lane];
    pre1 = P[(w*4 + 1)*64 + lane];
    pre2 = P[(w*4 + 2)*64 + lane];
    pre3 = P[(w*4 + 3)*64 + lane];
    for (int g=0; g<NG; ++g){
        __syncthreads();
        sPos[(w*4    )*64 + lane] = pre0;
        sPos[(w*4 + 1)*64 + lane] = pre1;
        sPos[(w*4 + 2)*64 + lane] = pre2;
        sPos[(w*4 + 3)*64 + lane] = pre3;
        if (g+1 < NG){
            pre0 = P[((g+1)*GT + w*4    )*64 + lane];
            pre1 = P[((g+1)*GT + w*4 + 1)*64 + lane];
            pre2 = P[((g+1)*GT + w*4 + 2)*64 + lane];
            pre3 = P[((g+1)*GT + w*4 + 3)*64 + lane];
        }
        __syncthreads();
        int tbase = g*GT;
        #pragma unroll 4
        for (int t=0;t<GT;t++){
            int tile = tbase + t;
            float4 q = sPos[t*64 + lane];
            int j = (tile<<6) + lane;
            bool selft = (tile == selfTile);
            DIST4(q)
            float d2a[4] = { d01.x, d01.y, d23.x, d23.y };
            #pragma unroll
            for (int k=0;k<4;k++){
                float d2 = d2a[k];
                bool hit = (d2 <= T[k]);
                if (selft && (lane == sl0 + k)) hit = false;
                unsigned long long m = __ballot(hit);
                if (m){
                    if (hit){
                        int off = cnt[k] + (int)__popcll(m & lt);
                        if (off < 64)
                            sCand[(w*4+k)*64 + off] = make_float2(d2, __int_as_float(j));
                    }
                    cnt[k] += (int)__popcll(m);
                }
            }
        }
    }

    // ---- sort each node's candidates (same-wave data; no barrier needed) ----
    #pragma unroll
    for (int k=0;k<4;k++){
        int m = cnt[k]; if (m > 64) m = 64;
        float d; int idx;
        if (lane < m){
            float2 e = sCand[(w*4+k)*64 + lane];
            d = e.x; idx = __float_as_int(e.y);
        } else { d = BIG; idx = 0x7f000000 + lane; }
        #pragma unroll
        for (int K=2; K<=64; K<<=1){
            #pragma unroll
            for (int j=K>>1; j>0; j>>=1){
                float od = __shfl_xor(d, j);
                int   oi = __shfl_xor(idx, j);
                bool pless = (od < d) || (od == d && oi < idx);
                bool keepmin = (((lane & j) == 0) == ((lane & K) == 0));
                if (pless == keepmin){ d = od; idx = oi; }
            }
        }
        if (lane < KNN) nbr[(size_t)(n0g + w*4 + k)*KNN + lane] = idx;
    }
}

// ---------------- K3: fused edge MLP + softmax-aggregate + node MLP + output ----------------
// 1024 blocks x 320 threads; block owns 16 nodes = 320 edges exactly. (R4-proven structure;
// C-budget is insensitive to all edgenode variants tried — keep the best-measured one.)
__global__ __launch_bounds__(320) void edgenode_kernel(const float4* __restrict__ pos4,
        const float4* __restrict__ vel4,
        const int* __restrict__ nbr,
        const float* __restrict__ pack,
        const float* __restrict__ consts,
        const float* __restrict__ Wn1,
        const float* __restrict__ Wn2,
        const float* __restrict__ be2,
        const float* __restrict__ bn2,
        const float* __restrict__ alpha_p,
        const float* __restrict__ beta_p,
        const float* __restrict__ z,
        float* __restrict__ out){
    __shared__ float4 sP[384];                       // 6 KB edge weights
    __shared__ float sLg[320], sSm[320], sUx[320], sUy[320], sUz[320];  // 6.25 KB
    __shared__ float sD[64], sT1[64], sW36[64], sWo[64];
    __shared__ float sMf[16];
    __shared__ float4 sAgg[16];                      // {vax,vay,vaz,sagg}
    __shared__ float sPart[320];

    int tid = threadIdx.x;
    bool bb = (blockIdx.x >= 512);                   // batch block-uniform
    for (int k=tid; k<384; k+=320) sP[k] = ((const float4*)pack)[k];
    if (tid < 64){
        sD[tid]   = consts[512 + (bb?64:0) + tid];
        sT1[tid]  = consts[640+tid];
        sW36[tid] = Wn1[36*64+tid];
        sWo[tid]  = Wn2[tid];
    }

    int e = blockIdx.x*320 + tid;
    int i = e / KNN;                   // global tgt node
    int ln = tid / KNN;                // local node 0..15
    int r  = tid - ln*KNN;             // edge rank 0..19
    int bbase = bb ? NB : 0;
    int s = nbr[e];
    float4 ps = pos4[bbase + s], pt = pos4[i];
    float4 vs = vel4[bbase + s], vt = vel4[i];
    if (r == 0) sMf[ln] = vt.w;

    float rx = ps.x - pt.x, ry = ps.y - pt.y, rz = ps.z - pt.z;
    float r2  = rx*rx + ry*ry + rz*rz;
    float vv  = vs.x*vt.x + vs.y*vt.y + vs.z*vt.z;
    float vsr = vs.x*rx + vs.y*ry + vs.z*rz;
    float vtr = vt.x*rx + vt.y*ry + vt.z*rz;
    float mfs = vs.w, mft = vt.w;
    __syncthreads();   // sP ready

    float a0 = be2[0], a1 = be2[1], a2 = be2[2], a3 = be2[3];
    #pragma unroll 4
    for (int h=0; h<128; h++){
        float4 A  = sP[h*3];
        float4 Bv = sP[h*3+1];
        float4 C  = sP[h*3+2];
        float base = bb ? A.y : A.x;
        float x = base + mfs*A.z + mft*A.w + r2*Bv.x + vv*Bv.y + vsr*Bv.z + vtr*Bv.w;
        float gx = gelu_f(x);
        a0 += gx*C.x; a1 += gx*C.y; a2 += gx*C.z; a3 += gx*C.w;
    }
    sLg[tid] = a0;
    sSm[tid] = a1;
    sUx[tid] = a2*rx + a3*vs.x;
    sUy[tid] = a2*ry + a3*vs.y;
    sUz[tid] = a2*rz + a3*vs.z;
    __syncthreads();

    // per-node softmax + aggregation (16 serial lanes)
    if (tid < 16){
        int base = tid*KNN;
        float m = -BIG;
        #pragma unroll
        for (int q=0;q<KNN;q++) m = fmaxf(m, sLg[base+q]);
        float den=0.f, wx=0.f, wy=0.f, wz=0.f, wsm=0.f;
        #pragma unroll
        for (int q=0;q<KNN;q++){
            float a = __expf(sLg[base+q]-m);
            den += a;
            wsm += a*sSm[base+q];
            wx  += a*sUx[base+q];
            wy  += a*sUy[base+q];
            wz  += a*sUz[base+q];
        }
        float inv = __fdividef(1.0f, den);
        sAgg[tid] = make_float4(wx*inv, wy*inv, wz*inv, wsm*inv);
    }
    __syncthreads();

    // node MLP partials: 20 threads per node, h = r, r+20, r+40, (r+60)
    {
        float mf = sMf[ln];
        float sg = sAgg[ln].w;
        float part = 0.f;
        #pragma unroll
        for (int h=r; h<64; h+=KNN){
            float x = sD[h] + mf*sT1[h] + sg*sW36[h];
            part += gelu_f(x)*sWo[h];
        }
        sPart[tid] = part;
    }
    __syncthreads();

    if (tid < 16){
        float sout = bn2[0];
        #pragma unroll
        for (int q=0;q<KNN;q++) sout += sPart[tid*KNN+q];
        int node = blockIdx.x*16 + tid;
        float alpha = alpha_p[0], beta = beta_p[0];
        float4 ag = sAgg[tid];
        const float* zp = z + (size_t)node*7;
        float* op = out + (size_t)node*7;
        op[0] = zp[0]*2.0f + alpha*ag.x;
        op[1] = zp[1]*2.0f + alpha*ag.y;
        op[2] = zp[2]*2.0f + alpha*ag.z;
        op[3] = zp[3] + beta*ag.x;
        op[4] = zp[4] + beta*ag.y;
        op[5] = zp[5] + beta*ag.z;
        op[6] = zp[6] + sout;
    }
}

extern "C" void kernel_launch(void* const* d_in, const int* in_sizes, int n_in,
                              void* d_out, int out_size, void* d_ws, size_t ws_size,
                              hipStream_t stream) {
    const float* z    = (const float*)d_in[0];
    const float* t    = (const float*)d_in[1];
    const float* cond = (const float*)d_in[2];
    const float* Wc1  = (const float*)d_in[4];
    const float* bc1  = (const float*)d_in[5];
    const float* Wc2  = (const float*)d_in[6];
    const float* bc2  = (const float*)d_in[7];
    const float* Wc3  = (const float*)d_in[8];
    const float* bc3  = (const float*)d_in[9];
    const float* We1  = (const float*)d_in[10];
    const float* be1  = (const float*)d_in[11];
    const float* We2  = (const float*)d_in[12];
    const float* be2  = (const float*)d_in[13];
    const float* Wn1  = (const float*)d_in[14];
    const float* bn1  = (const float*)d_in[15];
    const float* Wn2  = (const float*)d_in[16];
    const float* bn2  = (const float*)d_in[17];
    const float* alp  = (const float*)d_in[18];
    const float* bet  = (const float*)d_in[19];
    float* out = (float*)d_out;

    char* ws = (char*)d_ws;
    float4* pos4   = (float4*)(ws);                      // 262144 B
    float4* vel4   = (float4*)(ws + 262144);             // 262144 B
    float*  consts = (float*)(ws + 524288);              // 4096 B
    float*  pack   = (float*)(ws + 528384);              // 6144 B
    int*    nbr    = (int*)(ws + 534528);                // 1310720 B

    prepcond_kernel<<<dim3(BN/256), dim3(256), 0, stream>>>(z, t, cond,
        Wc1, bc1, Wc2, bc2, Wc3, bc3, We1, be1, We2, Wn1, bn1,
        pos4, vel4, consts, pack);
    knn_kernel<<<dim3(BN/32), dim3(512), 0, stream>>>(pos4, nbr);
    edgenode_kernel<<<dim3(BN/16), dim3(320), 0, stream>>>(pos4, vel4, nbr, pack, consts,
        Wn1, Wn2, be2, bn2, alp, bet, z, out);
}

// Round 8
// 199.302 us; speedup vs baseline: 1.1815x; 1.0177x over previous
//
#include <hip/hip_runtime.h>
#include <math.h>

#define NB 8192
#define BATCH 2
#define KNN 20
#define BN (BATCH*NB)
#define NE (BN*KNN)        // 327680 edges
#define GT 16              // tiles per staged group (16 KB) — R2-proven; GT=32 regressed (R6)
#define NG 8               // groups per pass
#define BIG 3.0e38f

// gelu(x) = x * sigmoid(2a) = x / (1 + exp(-2a));  -2a = x*(-1.5957691 - 0.07135482*x^2)
__device__ __forceinline__ float gelu_f(float x){
    float t = x*x;
    float m = x*fmaf(t, -0.0713548163f, -1.5957691216f);
    float e = __expf(m);
    return __fdividef(x, 1.0f + e);
}

// ---------------- K1: prep (all 64 blocks) + cond MLP (blocks 0,1) ----------------
// consts floats: C[2][128]@0, S1[128]@256, S2[128]@384, D[2][64]@512, T1[64]@640
// pack per h (128): {C0,C1,S1,S2, W72,W73,W74,W75, V0,V1,V2,V3} = 12 floats
__global__ __launch_bounds__(256) void prepcond_kernel(const float* __restrict__ z,
        const float* __restrict__ t,
        const float* __restrict__ conditioning,
        const float* __restrict__ Wc1, const float* __restrict__ bc1,
        const float* __restrict__ Wc2, const float* __restrict__ bc2,
        const float* __restrict__ Wc3, const float* __restrict__ bc3,
        const float* __restrict__ We1, const float* __restrict__ be1,
        const float* __restrict__ We2,
        const float* __restrict__ Wn1, const float* __restrict__ bn1,
        float4* __restrict__ pos4, float4* __restrict__ vel4,
        float* __restrict__ consts, float* __restrict__ pack){
    int tid = threadIdx.x;
    int g = blockIdx.x*256 + tid;
    const float* zp = z + (size_t)g*7;
    float x = zp[0], y = zp[1], zz = zp[2];
    float r2 = x*x + y*y + zz*zz;
    pos4[g] = make_float4(x, y, zz, r2);
    vel4[g] = make_float4(zp[3], zp[4], zp[5], zp[6]);

    if (blockIdx.x >= BATCH) return;
    int b = blockIdx.x;
    __shared__ float ci[36];
    __shared__ float h1[144];
    __shared__ float h2[144];
    __shared__ float cnd[36];
    float tv = t[b];
    if (tid < 16){
        float f = expf(-9.210340371976184f * (float)tid / 15.0f);
        float a = tv*f;
        ci[tid]    = sinf(a);
        ci[16+tid] = cosf(a);
    }
    if (tid < 4) ci[32+tid] = conditioning[b*4+tid];
    __syncthreads();
    if (tid < 144){
        float acc = bc1[tid];
        #pragma unroll
        for (int c=0;c<36;c++) acc += ci[c]*Wc1[c*144+tid];
        h1[tid] = gelu_f(acc);
    }
    __syncthreads();
    if (tid < 144){
        float acc = bc2[tid];
        #pragma unroll 36
        for (int c=0;c<144;c++) acc += h1[c]*Wc2[c*144+tid];
        h2[tid] = gelu_f(acc);
    }
    __syncthreads();
    if (tid < 36){
        float acc = bc3[tid];
        #pragma unroll 36
        for (int c=0;c<144;c++) acc += h2[c]*Wc3[c*36+tid];
        cnd[tid] = acc;
    }
    __syncthreads();
    if (tid < 128){
        float accC = be1[tid], s1 = 0.f, s2 = 0.f;
        #pragma unroll
        for (int c=0;c<36;c++){
            float w1 = We1[c*128+tid];
            float w2 = We1[(36+c)*128+tid];
            accC += cnd[c]*(w1+w2);
            s1 += w1; s2 += w2;
        }
        consts[b*128+tid] = accC;
        pack[tid*12 + b] = accC;
        if (b==0){
            consts[256+tid] = s1; consts[384+tid] = s2;
            pack[tid*12+2] = s1;
            pack[tid*12+3] = s2;
            pack[tid*12+4] = We1[72*128+tid];
            pack[tid*12+5] = We1[73*128+tid];
            pack[tid*12+6] = We1[74*128+tid];
            pack[tid*12+7] = We1[75*128+tid];
            pack[tid*12+8]  = We2[tid*4+0];
            pack[tid*12+9]  = We2[tid*4+1];
            pack[tid*12+10] = We2[tid*4+2];
            pack[tid*12+11] = We2[tid*4+3];
        }
    }
    if (tid < 64){
        float accD = bn1[tid], t1 = 0.f;
        #pragma unroll
        for (int c=0;c<36;c++){
            float w = Wn1[c*64+tid];
            accD += cnd[c]*w;
            t1 += w;
        }
        consts[512 + b*64 + tid] = accD;
        if (b==0) consts[640+tid] = t1;
    }
}

// ---------------- K2: fused KNN + select (proven two-pass), 8 waves x 4 nodes ----------------
// R2/R5-proven config (67.1 us): 512 thr, 4 nodes/wave, GT=16/NG=8, grid BN/32.
// DO NOT restructure — falsified variants: array prefetch (R1: scratch, 88MB writes),
// 8-node/wave (R3), 4x256thr (R4), f32x2+GT32 (R6: identical VALU-busy-time, +7.5us stalls;
// ext_vector f32 math does NOT contract to v_pk_fma on this compiler).
// Distance: per-target-shifted d2' = r_j^2 - 2 p_i.p_j (ordering-equivalent; threshold from
// same shifted values -> identical selection). Self excluded explicitly.
__global__ __launch_bounds__(512, 4) void knn_kernel(const float4* __restrict__ pos4,
                                                     int* __restrict__ nbr){
    __shared__ float4 sPos[GT*64];      // 16 KB
    __shared__ float2 sCand[32*64];     // 16 KB
    int tid = threadIdx.x;
    int w = tid >> 6, lane = tid & 63;
    int n0g = blockIdx.x * 32;
    int b = n0g >> 13;
    int n0 = n0g & (NB-1);
    const float4* __restrict__ P = pos4 + b*NB;

    int nw = n0 + w*4;
    float nx[4], ny[4], nz[4], acc[4];
    #pragma unroll
    for (int k=0;k<4;k++){
        float4 p = P[nw+k];
        nx[k] = -2.0f*p.x; ny[k] = -2.0f*p.y; nz[k] = -2.0f*p.z;
        acc[k] = BIG;
    }
    int selfTile = n0 >> 6;            // all 32 block nodes share one tile
    int sl0 = (n0 & 63) + w*4;         // self lane for node k is sl0+k

    // ---- Pass A ----
    float4 pre0 = P[(w*2    )*64 + lane];
    float4 pre1 = P[(w*2 + 1)*64 + lane];
    for (int g=0; g<NG; ++g){
        __syncthreads();
        sPos[(w*2    )*64 + lane] = pre0;
        sPos[(w*2 + 1)*64 + lane] = pre1;
        if (g+1 < NG){
            pre0 = P[((g+1)*GT + w*2    )*64 + lane];
            pre1 = P[((g+1)*GT + w*2 + 1)*64 + lane];
        }
        __syncthreads();
        int tbase = g*GT;
        #pragma unroll
        for (int t=0;t<GT;t++){
            float4 q = sPos[t*64 + lane];
            if (tbase + t != selfTile){
                #pragma unroll
                for (int k=0;k<4;k++){
                    float d2 = fmaf(nx[k],q.x, fmaf(ny[k],q.y, fmaf(nz[k],q.z, q.w)));
                    acc[k] = fminf(acc[k], d2);
                }
            } else {
                #pragma unroll
                for (int k=0;k<4;k++){
                    float d2 = fmaf(nx[k],q.x, fmaf(ny[k],q.y, fmaf(nz[k],q.z, q.w)));
                    if (lane == sl0 + k) d2 = BIG;
                    acc[k] = fminf(acc[k], d2);
                }
            }
        }
    }

    // ---- T[k] = 20th smallest of 64 per-lane minima ----
    float T[4];
    #pragma unroll
    for (int k=0;k<4;k++){
        float v = acc[k];
        #pragma unroll
        for (int K=2; K<=64; K<<=1){
            #pragma unroll
            for (int j=K>>1; j>0; j>>=1){
                float o = __shfl_xor(v, j);
                bool keepmin = (((lane & j) == 0) == ((lane & K) == 0));
                float mn = fminf(v,o), mx = fmaxf(v,o);
                v = keepmin ? mn : mx;
            }
        }
        T[k] = __shfl(v, 19);
    }

    // ---- Pass B: collect into LDS ----
    int cnt[4];
    #pragma unroll
    for (int k=0;k<4;k++) cnt[k] = 0;
    unsigned long long lt = (1ull << lane) - 1ull;

    pre0 = P[(w*2    )*64 + lane];
    pre1 = P[(w*2 + 1)*64 + lane];
    for (int g=0; g<NG; ++g){
        __syncthreads();
        sPos[(w*2    )*64 + lane] = pre0;
        sPos[(w*2 + 1)*64 + lane] = pre1;
        if (g+1 < NG){
            pre0 = P[((g+1)*GT + w*2    )*64 + lane];
            pre1 = P[((g+1)*GT + w*2 + 1)*64 + lane];
        }
        __syncthreads();
        int tbase = g*GT;
        #pragma unroll 4
        for (int t=0;t<GT;t++){
            int tile = tbase + t;
            float4 q = sPos[t*64 + lane];
            int j = (tile<<6) + lane;
            bool selft = (tile == selfTile);
            #pragma unroll
            for (int k=0;k<4;k++){
                float d2 = fmaf(nx[k],q.x, fmaf(ny[k],q.y, fmaf(nz[k],q.z, q.w)));
                bool hit = (d2 <= T[k]);
                if (selft && (lane == sl0 + k)) hit = false;
                unsigned long long m = __ballot(hit);
                if (m){
                    if (hit){
                        int off = cnt[k] + (int)__popcll(m & lt);
                        if (off < 64)
                            sCand[(w*4+k)*64 + off] = make_float2(d2, __int_as_float(j));
                    }
                    cnt[k] += (int)__popcll(m);
                }
            }
        }
    }

    // ---- sort each node's candidates (same-wave data; no barrier needed) ----
    #pragma unroll
    for (int k=0;k<4;k++){
        int m = cnt[k]; if (m > 64) m = 64;
        float d; int idx;
        if (lane < m){
            float2 e = sCand[(w*4+k)*64 + lane];
            d = e.x; idx = __float_as_int(e.y);
        } else { d = BIG; idx = 0x7f000000 + lane; }
        #pragma unroll
        for (int K=2; K<=64; K<<=1){
            #pragma unroll
            for (int j=K>>1; j>0; j>>=1){
                float od = __shfl_xor(d, j);
                int   oi = __shfl_xor(idx, j);
                bool pless = (od < d) || (od == d && oi < idx);
                bool keepmin = (((lane & j) == 0) == ((lane & K) == 0));
                if (pless == keepmin){ d = od; idx = oi; }
            }
        }
        if (lane < KNN) nbr[(size_t)(n0g + w*4 + k)*KNN + lane] = idx;
    }
}

// ---------------- K3: fused edge MLP + softmax-aggregate + node MLP + output ----------------
// 1024 blocks x 320 threads; block owns 16 nodes = 320 edges exactly.
// Best-measured variant (R6: C = total - knn = 128.2 us): 1 edge/thread, LDS weights,
// fast gelu. Falsified: scalar-path weights (R2: +6us), 2-edge/thread (R5: +3us).
__global__ __launch_bounds__(320) void edgenode_kernel(const float4* __restrict__ pos4,
        const float4* __restrict__ vel4,
        const int* __restrict__ nbr,
        const float* __restrict__ pack,
        const float* __restrict__ consts,
        const float* __restrict__ Wn1,
        const float* __restrict__ Wn2,
        const float* __restrict__ be2,
        const float* __restrict__ bn2,
        const float* __restrict__ alpha_p,
        const float* __restrict__ beta_p,
        const float* __restrict__ z,
        float* __restrict__ out){
    __shared__ float4 sP[384];                       // 6 KB edge weights
    __shared__ float sLg[320], sSm[320], sUx[320], sUy[320], sUz[320];  // 6.25 KB
    __shared__ float sD[64], sT1[64], sW36[64], sWo[64];
    __shared__ float sMf[16];
    __shared__ float4 sAgg[16];                      // {vax,vay,vaz,sagg}
    __shared__ float sPart[320];

    int tid = threadIdx.x;
    bool bb = (blockIdx.x >= 512);                   // batch block-uniform
    for (int k=tid; k<384; k+=320) sP[k] = ((const float4*)pack)[k];
    if (tid < 64){
        sD[tid]   = consts[512 + (bb?64:0) + tid];
        sT1[tid]  = consts[640+tid];
        sW36[tid] = Wn1[36*64+tid];
        sWo[tid]  = Wn2[tid];
    }

    int e = blockIdx.x*320 + tid;
    int i = e / KNN;                   // global tgt node
    int ln = tid / KNN;                // local node 0..15
    int r  = tid - ln*KNN;             // edge rank 0..19
    int bbase = bb ? NB : 0;
    int s = nbr[e];
    float4 ps = pos4[bbase + s], pt = pos4[i];
    float4 vs = vel4[bbase + s], vt = vel4[i];
    if (r == 0) sMf[ln] = vt.w;

    float rx = ps.x - pt.x, ry = ps.y - pt.y, rz = ps.z - pt.z;
    float r2  = rx*rx + ry*ry + rz*rz;
    float vv  = vs.x*vt.x + vs.y*vt.y + vs.z*vt.z;
    float vsr = vs.x*rx + vs.y*ry + vs.z*rz;
    float vtr = vt.x*rx + vt.y*ry + vt.z*rz;
    float mfs = vs.w, mft = vt.w;
    __syncthreads();   // sP ready

    float a0 = be2[0], a1 = be2[1], a2 = be2[2], a3 = be2[3];
    #pragma unroll 4
    for (int h=0; h<128; h++){
        float4 A  = sP[h*3];
        float4 Bv = sP[h*3+1];
        float4 C  = sP[h*3+2];
        float base = bb ? A.y : A.x;
        float x = base + mfs*A.z + mft*A.w + r2*Bv.x + vv*Bv.y + vsr*Bv.z + vtr*Bv.w;
        float gx = gelu_f(x);
        a0 += gx*C.x; a1 += gx*C.y; a2 += gx*C.z; a3 += gx*C.w;
    }
    sLg[tid] = a0;
    sSm[tid] = a1;
    sUx[tid] = a2*rx + a3*vs.x;
    sUy[tid] = a2*ry + a3*vs.y;
    sUz[tid] = a2*rz + a3*vs.z;
    __syncthreads();

    // per-node softmax + aggregation (16 serial lanes)
    if (tid < 16){
        int base = tid*KNN;
        float m = -BIG;
        #pragma unroll
        for (int q=0;q<KNN;q++) m = fmaxf(m, sLg[base+q]);
        float den=0.f, wx=0.f, wy=0.f, wz=0.f, wsm=0.f;
        #pragma unroll
        for (int q=0;q<KNN;q++){
            float a = __expf(sLg[base+q]-m);
            den += a;
            wsm += a*sSm[base+q];
            wx  += a*sUx[base+q];
            wy  += a*sUy[base+q];
            wz  += a*sUz[base+q];
        }
        float inv = __fdividef(1.0f, den);
        sAgg[tid] = make_float4(wx*inv, wy*inv, wz*inv, wsm*inv);
    }
    __syncthreads();

    // node MLP partials: 20 threads per node, h = r, r+20, r+40, (r+60)
    {
        float mf = sMf[ln];
        float sg = sAgg[ln].w;
        float part = 0.f;
        #pragma unroll
        for (int h=r; h<64; h+=KNN){
            float x = sD[h] + mf*sT1[h] + sg*sW36[h];
            part += gelu_f(x)*sWo[h];
        }
        sPart[tid] = part;
    }
    __syncthreads();

    if (tid < 16){
        float sout = bn2[0];
        #pragma unroll
        for (int q=0;q<KNN;q++) sout += sPart[tid*KNN+q];
        int node = blockIdx.x*16 + tid;
        float alpha = alpha_p[0], beta = beta_p[0];
        float4 ag = sAgg[tid];
        const float* zp = z + (size_t)node*7;
        float* op = out + (size_t)node*7;
        op[0] = zp[0]*2.0f + alpha*ag.x;
        op[1] = zp[1]*2.0f + alpha*ag.y;
        op[2] = zp[2]*2.0f + alpha*ag.z;
        op[3] = zp[3] + beta*ag.x;
        op[4] = zp[4] + beta*ag.y;
        op[5] = zp[5] + beta*ag.z;
        op[6] = zp[6] + sout;
    }
}

extern "C" void kernel_launch(void* const* d_in, const int* in_sizes, int n_in,
                              void* d_out, int out_size, void* d_ws, size_t ws_size,
                              hipStream_t stream) {
    const float* z    = (const float*)d_in[0];
    const float* t    = (const float*)d_in[1];
    const float* cond = (const float*)d_in[2];
    const float* Wc1  = (const float*)d_in[4];
    const float* bc1  = (const float*)d_in[5];
    const float* Wc2  = (const float*)d_in[6];
    const float* bc2  = (const float*)d_in[7];
    const float* Wc3  = (const float*)d_in[8];
    const float* bc3  = (const float*)d_in[9];
    const float* We1  = (const float*)d_in[10];
    const float* be1  = (const float*)d_in[11];
    const float* We2  = (const float*)d_in[12];
    const float* be2  = (const float*)d_in[13];
    const float* Wn1  = (const float*)d_in[14];
    const float* bn1  = (const float*)d_in[15];
    const float* Wn2  = (const float*)d_in[16];
    const float* bn2  = (const float*)d_in[17];
    const float* alp  = (const float*)d_in[18];
    const float* bet  = (const float*)d_in[19];
    float* out = (float*)d_out;

    char* ws = (char*)d_ws;
    float4* pos4   = (float4*)(ws);                      // 262144 B
    float4* vel4   = (float4*)(ws + 262144);             // 262144 B
    float*  consts = (float*)(ws + 524288);              // 4096 B
    float*  pack   = (float*)(ws + 528384);              // 6144 B
    int*    nbr    = (int*)(ws + 534528);                // 1310720 B

    prepcond_kernel<<<dim3(BN/256), dim3(256), 0, stream>>>(z, t, cond,
        Wc1, bc1, Wc2, bc2, Wc3, bc3, We1, be1, We2, Wn1, bn1,
        pos4, vel4, consts, pack);
    knn_kernel<<<dim3(BN/32), dim3(512), 0, stream>>>(pos4, nbr);
    edgenode_kernel<<<dim3(BN/16), dim3(320), 0, stream>>>(pos4, vel4, nbr, pack, consts,
        Wn1, Wn2, be2, bn2, alp, bet, z, out);
}